// Round 3
// baseline (140.125 us; speedup 1.0000x reference)
//
#include <hip/hip_runtime.h>
#include <math.h>

#define TB   256
#define HH   128      // input H=W
#define OHW  64       // output H=W
#define TR   16       // output rows per tile
#define NT   4        // tiles per plane (64/16)
#define N0R  18       // n0 rows incl. 1-halo
#define N0C  66       // n0 cols incl. 1-halo

__device__ __forceinline__ float sigmoidf(float z) {
    return 1.0f / (1.0f + __expf(-z));
}

__global__ __launch_bounds__(TB) void fused_densenet_kernel(
    const float* __restrict__ x,
    const float* __restrict__ maxgate,
    const float* __restrict__ mb,
    const float* __restrict__ pconvs,
    const float* __restrict__ pbs,
    const float* __restrict__ pgates,
    const float* __restrict__ gbs,
    float* __restrict__ out)
{
    __shared__ float n0s[N0R][N0C];   // only n0 goes through LDS (4.75 KB)

    const int t     = threadIdx.x;
    const int lane  = t & 63;         // output col
    const int w     = t >> 6;         // wave id (4 waves)
    const int bid   = blockIdx.x;
    const int tile  = bid & (NT - 1);
    const int plane = bid >> 2;       // b*256 + c
    const int c     = plane & 255;
    const int r0    = tile * TR;

    // ---- uniform weights/biases (block-uniform address -> scalar loads) ----
    // ws rows: 0=maxgate 1=p0 2=p1 3=p2 4=p3 5=gate0 6=gate2(leaf1+node)
    float ws[7][9];
#pragma unroll
    for (int i = 0; i < 9; ++i) {
        ws[0][i] = maxgate[c * 9  + i];
        ws[1][i] = pconvs [c * 36 + i * 4 + 0];
        ws[2][i] = pconvs [c * 36 + i * 4 + 1];
        ws[3][i] = pconvs [c * 36 + i * 4 + 2];
        ws[4][i] = pconvs [c * 36 + i * 4 + 3];
        ws[5][i] = pgates [c * 27 + i * 3 + 0];
        ws[6][i] = pgates [c * 27 + i * 3 + 2];
    }
    const float bmax = mb[c];
    const float bp0 = pbs[c * 4 + 0], bp1 = pbs[c * 4 + 1];
    const float bp2 = pbs[c * 4 + 2], bp3 = pbs[c * 4 + 3];
    const float bg0 = gbs[c * 3 + 0];   // leaf0 gate bias
    const float bg1 = gbs[c * 3 + 1];   // leaf1 gate bias
    const float bg2 = gbs[c * 3 + 2];   // node gate bias

    const float* xp = x + (size_t)plane * (HH * HH);

    // ---- stage 1: direct-from-global, 4 output rows per thread ----
    float out1k[4], n1k[4], n0k[4];
#pragma unroll
    for (int k = 0; k < 4; ++k) {
        const int lr = 4 * k + w;      // local output row 0..15
        const int gr = r0 + lr;
        float acc[7];
#pragma unroll
        for (int ci = 0; ci < 7; ++ci) acc[ci] = 0.f;
        float mp = -INFINITY;

#pragma unroll
        for (int dr = 0; dr < 3; ++dr) {
            const int ir = 2 * gr - 1 + dr;      // ir <= 127 always
            if (ir >= 0) {                        // wave-uniform (only gr==0,dr==0 fails)
                const float* rp = xp + ir * HH;
                float av = 0.f;
                if (lane > 0) av = rp[2 * lane - 1];
                const float2 d2 = *reinterpret_cast<const float2*>(&rp[2 * lane]);
                // maxpool (pad = -inf; left col OOB only)
                const float m0 = (lane > 0) ? av : -INFINITY;
                mp = fmaxf(mp, fmaxf(fmaxf(m0, d2.x), d2.y));
                // convs (zero pad; av already 0 at left edge)
#pragma unroll
                for (int ci = 0; ci < 7; ++ci)
                    acc[ci] += av   * ws[ci][3 * dr]
                             + d2.x * ws[ci][3 * dr + 1]
                             + d2.y * ws[ci][3 * dr + 2];
            }
        }
        const float sg0 = sigmoidf(acc[5] + bg0);
        const float n0v = sg0 * (acc[1] + bp0) + (1.f - sg0) * (acc[2] + bp1);
        const float sg1 = sigmoidf(acc[6] + bg1);      // leaf1 gate: bias gbs[:,1]
        n1k[k]   = sg1 * (acc[3] + bp2) + (1.f - sg1) * (acc[4] + bp3);
        out1k[k] = mp * (acc[0] + bmax);
        n0k[k]   = n0v;
        n0s[lr + 1][lane + 1] = n0v;
    }

    // ---- n0 halo rows (top/bottom; zero outside image) ----
    if (t < 128) {
        const int gr = (t < 64) ? (r0 - 1) : (r0 + TR);
        const int cc = t & 63;
        const int lr = (t < 64) ? 0 : (TR + 1);
        float n0v = 0.f;
        if ((unsigned)gr < (unsigned)OHW) {
            float a1 = 0.f, a2 = 0.f, a5 = 0.f;
#pragma unroll
            for (int dr = 0; dr < 3; ++dr) {
                const int ir = 2 * gr - 1 + dr;
                if (ir >= 0) {
                    const float* rp = xp + ir * HH;
                    float av = 0.f;
                    if (cc > 0) av = rp[2 * cc - 1];
                    const float2 d2 = *reinterpret_cast<const float2*>(&rp[2 * cc]);
                    a1 += av * ws[1][3 * dr] + d2.x * ws[1][3 * dr + 1] + d2.y * ws[1][3 * dr + 2];
                    a2 += av * ws[2][3 * dr] + d2.x * ws[2][3 * dr + 1] + d2.y * ws[2][3 * dr + 2];
                    a5 += av * ws[5][3 * dr] + d2.x * ws[5][3 * dr + 1] + d2.y * ws[5][3 * dr + 2];
                }
            }
            const float sg = sigmoidf(a5 + bg0);
            n0v = sg * (a1 + bp0) + (1.f - sg) * (a2 + bp1);
        }
        n0s[lr][cc + 1] = n0v;
    } else if (t < 128 + 2 * N0R) {
        const int i = t - 128;                      // side cols are outside image -> 0
        n0s[i >> 1][(i & 1) ? (N0C - 1) : 0] = 0.f;
    }
    __syncthreads();

    // ---- stage 2: node gate conv on n0 (stride 1, pad 1) + combine + store ----
    float* op = out + (size_t)plane * (OHW * OHW);
#pragma unroll
    for (int k = 0; k < 4; ++k) {
        const int lr = 4 * k + w;
        float ag = 0.f;
#pragma unroll
        for (int dr = 0; dr < 3; ++dr) {
            ag += n0s[lr + dr][lane]     * ws[6][3 * dr]
                + n0s[lr + dr][lane + 1] * ws[6][3 * dr + 1]
                + n0s[lr + dr][lane + 2] * ws[6][3 * dr + 2];
        }
        const float g = sigmoidf(ag + bg2);         // node gate: bias gbs[:,2]
        op[(r0 + lr) * OHW + lane] = out1k[k] + n0k[k] * g + n1k[k] * (1.f - g);
    }
}

extern "C" void kernel_launch(void* const* d_in, const int* in_sizes, int n_in,
                              void* d_out, int out_size, void* d_ws, size_t ws_size,
                              hipStream_t stream) {
    const float* x       = (const float*)d_in[0];
    const float* maxgate = (const float*)d_in[1];
    const float* mb      = (const float*)d_in[2];
    const float* pconvs  = (const float*)d_in[3];
    const float* pbs     = (const float*)d_in[4];
    const float* pgates  = (const float*)d_in[5];
    const float* gbs     = (const float*)d_in[6];
    float* out           = (float*)d_out;

    const int blocks = 16 * 256 * NT;   // B * C * tiles-per-plane
    fused_densenet_kernel<<<blocks, TB, 0, stream>>>(
        x, maxgate, mb, pconvs, pbs, pgates, gbs, out);
}

// Round 4
// 86.886 us; speedup vs baseline: 1.6127x; 1.6127x over previous
//
#include <hip/hip_runtime.h>
#include <math.h>

#define TB   512
#define HH   128      // input H=W
#define OHW  64       // output H=W
#define TR   32       // output rows per tile
#define NT   2        // tiles per plane (64/32)
#define XR   69       // input rows staged: 2*TR+5
#define XC   136      // 128 cols + pad (col offset +4, zeros in pad)
#define N0R  34       // n0 rows incl. 1-halo
#define N0C  68       // n0 row stride (66 used)

__device__ __forceinline__ float sigmoidf(float z) {
    return 1.0f / (1.0f + __expf(-z));
}

__global__ __launch_bounds__(TB) void fused_densenet_kernel(
    const float* __restrict__ x,
    const float* __restrict__ maxgate,
    const float* __restrict__ mb,
    const float* __restrict__ pconvs,
    const float* __restrict__ pbs,
    const float* __restrict__ pgates,
    const float* __restrict__ gbs,
    float* __restrict__ out)
{
    __shared__ float xs[XR][XC];       // input slab, zero-padded (37.5 KB)
    __shared__ float n0s[N0R][N0C];    // n0 with 1-halo (9.25 KB)

    const int t     = threadIdx.x;
    const int bid   = blockIdx.x;
    const int tile  = bid & (NT - 1);
    const int plane = bid >> 1;        // b*256 + c
    const int c     = plane & 255;
    const int r0    = tile * TR;       // first global output row of tile

    // ---- uniform weights/biases (block-uniform address -> SGPR-resident) ----
    // ws rows: 0=maxgate 1=p0 2=p1 3=p2 4=p3 5=gate0 6=gate2(leaf1+node)
    float ws[7][9];
#pragma unroll
    for (int i = 0; i < 9; ++i) {
        ws[0][i] = maxgate[c * 9  + i];
        ws[1][i] = pconvs [c * 36 + i * 4 + 0];
        ws[2][i] = pconvs [c * 36 + i * 4 + 1];
        ws[3][i] = pconvs [c * 36 + i * 4 + 2];
        ws[4][i] = pconvs [c * 36 + i * 4 + 3];
        ws[5][i] = pgates [c * 27 + i * 3 + 0];
        ws[6][i] = pgates [c * 27 + i * 3 + 2];
    }
    const float bmax = mb[c];
    const float bp0 = pbs[c * 4 + 0], bp1 = pbs[c * 4 + 1];
    const float bp2 = pbs[c * 4 + 2], bp3 = pbs[c * 4 + 3];
    const float bg0 = gbs[c * 3 + 0];   // leaf0 gate bias
    const float bg1 = gbs[c * 3 + 1];   // leaf1 gate bias
    const float bg2 = gbs[c * 3 + 2];   // node gate bias

    // ---- global -> LDS: rows [2*r0-3 , 2*r0+65], cols -4..131 (zero pad) ----
    const float* xplane = x + (size_t)plane * (HH * HH);
    const int ir0 = 2 * r0 - 3;
    for (int s = t; s < XR * 34; s += TB) {       // 34 float4 slots per row
        const int rr = s / 34;
        const int qq = s - rr * 34;
        float4 v = make_float4(0.f, 0.f, 0.f, 0.f);
        const int ir = ir0 + rr;
        if (qq >= 1 && qq <= 32 && (unsigned)ir < (unsigned)HH) {
            v = *reinterpret_cast<const float4*>(xplane + ir * HH + (qq - 1) * 4);
        }
        *reinterpret_cast<float4*>(&xs[rr][qq * 4]) = v;   // 16B-aligned
    }
    __syncthreads();

    // ---- halo ring of n0 (34x66 grid minus 32x64 interior = 196 positions) ----
    if (t < 196) {
        int lrr, lc;
        if (t < 66)        { lrr = 0;        lc = t;       }
        else if (t < 132)  { lrr = N0R - 1;  lc = t - 66;  }
        else { const int i = t - 132; lrr = 1 + (i >> 1); lc = (i & 1) ? 65 : 0; }
        const int gr = r0 - 1 + lrr;   // global output row of this n0 entry
        const int gc = lc - 1;         // global output col
        float n0v = 0.f;               // stage-2 conv zero-pads n0 at image edge
        if ((unsigned)gr < (unsigned)OHW && (unsigned)gc < (unsigned)OHW) {
            float ag = 0.f, a0 = 0.f, a1 = 0.f;
#pragma unroll
            for (int dr = 0; dr < 3; ++dr)
#pragma unroll
                for (int dc = 0; dc < 3; ++dc) {
                    const float v = xs[2 * lrr + dr][2 * lc + dc + 1];
                    const int i = dr * 3 + dc;
                    ag += v * ws[5][i];
                    a0 += v * ws[1][i];
                    a1 += v * ws[2][i];
                }
            const float sg = sigmoidf(ag + bg0);
            n0v = sg * (a0 + bp0) + (1.f - sg) * (a1 + bp1);
        }
        n0s[lrr][lc] = n0v;
    }

    // ---- interior: all 7 convs + maxpool from one shared 3x3 window ----
    const int lc64 = t & 63;          // output col (whole wave: same row)
    const int wq   = t >> 6;          // 0..7
    float out1[4], n1[4], n0k[4];
#pragma unroll
    for (int k = 0; k < 4; ++k) {
        const int lr = wq + 8 * k;    // local output row 0..31
        const int gr = r0 + lr;
        const int gc = lc64;

        float w9[9];
#pragma unroll
        for (int dr = 0; dr < 3; ++dr)
#pragma unroll
            for (int dc = 0; dc < 3; ++dc)
                w9[dr * 3 + dc] = xs[2 * lr + dr + 2][2 * lc64 + dc + 3];

        float mp = -INFINITY;
        float amax = 0.f, a0 = 0.f, a1 = 0.f, a2 = 0.f, a3 = 0.f;
        float ag0 = 0.f, ag2 = 0.f;
#pragma unroll
        for (int i = 0; i < 9; ++i) {
            const int dr = i / 3, dc = i % 3;
            const float v = w9[i];
            amax += v * ws[0][i];
            a0   += v * ws[1][i];
            a1   += v * ws[2][i];
            a2   += v * ws[3][i];
            a3   += v * ws[4][i];
            ag0  += v * ws[5][i];
            ag2  += v * ws[6][i];
            // maxpool pads with -inf; only low edges can be out of range here
            const bool valid = ((gr > 0) | (dr > 0)) & ((gc > 0) | (dc > 0));
            mp = fmaxf(mp, valid ? v : -INFINITY);
        }
        const float sg0 = sigmoidf(ag0 + bg0);
        const float n0v = sg0 * (a0 + bp0) + (1.f - sg0) * (a1 + bp1);
        n0k[k] = n0v;
        n0s[lr + 1][lc64 + 1] = n0v;
        const float sg1 = sigmoidf(ag2 + bg1);          // leaf1 gate: bias gbs[:,1]
        n1[k]   = sg1 * (a2 + bp2) + (1.f - sg1) * (a3 + bp3);
        out1[k] = mp * (amax + bmax);
    }
    __syncthreads();

    // ---- stage 2: node gate conv on n0 (stride 1, pad 1) + combine + store ----
    float* oplane = out + (size_t)plane * (OHW * OHW);
#pragma unroll
    for (int k = 0; k < 4; ++k) {
        const int lr = wq + 8 * k;
        float ag = 0.f;
#pragma unroll
        for (int dr = 0; dr < 3; ++dr)
            ag += n0s[lr + dr][lc64]     * ws[6][3 * dr]
                + n0s[lr + dr][lc64 + 1] * ws[6][3 * dr + 1]
                + n0s[lr + dr][lc64 + 2] * ws[6][3 * dr + 2];
        const float g = sigmoidf(ag + bg2);             // node gate: bias gbs[:,2]
        const float r = out1[k] + n0k[k] * g + n1[k] * (1.f - g);
        __builtin_nontemporal_store(r, &oplane[(r0 + lr) * OHW + lc64]);
    }
}

extern "C" void kernel_launch(void* const* d_in, const int* in_sizes, int n_in,
                              void* d_out, int out_size, void* d_ws, size_t ws_size,
                              hipStream_t stream) {
    const float* x       = (const float*)d_in[0];
    const float* maxgate = (const float*)d_in[1];
    const float* mb      = (const float*)d_in[2];
    const float* pconvs  = (const float*)d_in[3];
    const float* pbs     = (const float*)d_in[4];
    const float* pgates  = (const float*)d_in[5];
    const float* gbs     = (const float*)d_in[6];
    float* out           = (float*)d_out;

    const int blocks = 16 * 256 * NT;   // B * C * tiles-per-plane
    fused_densenet_kernel<<<blocks, TB, 0, stream>>>(
        x, maxgate, mb, pconvs, pbs, pgates, gbs, out);
}